// Round 12
// baseline (77.289 us; speedup 1.0000x reference)
//
#include <hip/hip_runtime.h>

// Simple_TensorProduct (e3nn uvw TP, MUL=256, l<=1, v=1) as two fused bf16 GEMMs.
//   out0[z,w]      = sum_k T0[z,k]    * B0[k,w]   (K=512)
//   out1[(z,c),w]  = sum_k T1[(z,c),k]* B1[k,w]   (K=768, M=3N)
//
// R12: ZERO-BARRIER design. One wave = one (16-z-row x 64-col) output tile,
// 8 u-chunks of 32. Wave-private 11.25 KB LDS region (4 waves x 11.25 = 45 KB)
// -> build/gemm ordering is within-wave lgkmcnt only; NO s_barrier anywhere.
// Waves drift freely: one wave's build (VALU) overlaps another's MFMA.
// Per-wave asm-load pipeline (R10-proven): burstB -> vmcnt(20) -> build ->
// issue next x1 -> vmcnt(8) -> gemm. u=32 makes kt==seg (simplest fragments).

typedef short bf16x8 __attribute__((ext_vector_type(8)));
typedef float f32x4 __attribute__((ext_vector_type(4)));
typedef int   ni4   __attribute__((ext_vector_type(4)));

static __device__ __forceinline__ unsigned short f2bf(float f) {
  unsigned int u = __builtin_bit_cast(unsigned int, f);
  u += 0x7FFFu + ((u >> 16) & 1u);   // RNE
  return (unsigned short)(u >> 16);
}

static __device__ __forceinline__ bf16x8 asbf(int4 v) {
  return __builtin_bit_cast(bf16x8, v);
}
static __device__ __forceinline__ bf16x8 asbfn(ni4 v) {
  return __builtin_bit_cast(bf16x8, v);
}

static __device__ __forceinline__ void gload4(ni4& dst, const void* p) {
  asm volatile("global_load_dwordx4 %0, %1, off" : "=v"(dst) : "v"(p));
}

#define WAITV(n) do { \
    asm volatile("s_waitcnt vmcnt(" #n ")"); \
    __builtin_amdgcn_sched_barrier(0); \
  } while (0)

// ---------------------------------------------------------------------------
// Weight prep: u-chunk = 32, c in 0..7. kt==seg within each chunk.
// B1: fid = ((c*3+kt)*16+ct)*64+lane  (24576 frags)
//   elem e: kc = kt*32+(lane>>4)*8+e (0..95), seg=kc>>5, u=c*32+(kc&31),
//   w=ct*16+(lane&15); seg0->W2, seg1->W3 (A1/sqrt3), seg2->W5 (A1/sqrt6)
// B0: fid = 24576 + ((c*2+kt)*16+ct)*64+lane  (16384 frags)
//   kc 0..63, seg=kc>>5; seg0->W1 (A0), seg1->W4 (A0/sqrt3)
// ---------------------------------------------------------------------------
__global__ __launch_bounds__(256) void prep_weights(
    const float* __restrict__ wgt, unsigned short* __restrict__ Bw)
{
  int fid = blockIdx.x * 256 + threadIdx.x;
  union { unsigned short h[8]; int4 v; } pk;
  if (fid < 24576) {
    int lane = fid & 63;
    int ct = (fid >> 6) & 15;
    int q = fid >> 10;            // 0..23 = c*3 + kt
    int kt = q % 3, c = q / 3;
    int w = ct * 16 + (lane & 15);
    int kh = (lane >> 4) * 8;
#pragma unroll
    for (int e = 0; e < 8; ++e) {
      int kc = kt * 32 + kh + e;       // 0..95
      int seg = kc >> 5;
      int u = c * 32 + (kc & 31);
      float s  = (seg == 2) ? 0.025515518153991442f : 0.03608439182435161f;
      int off  = (seg == 0) ? 65536 : (seg == 1 ? 131072 : 262144);
      pk.h[e] = f2bf(wgt[off + u * 256 + w] * s);
    }
    ((int4*)Bw)[fid] = pk.v;
  } else if (fid < 40960) {
    int f2 = fid - 24576;
    int lane = f2 & 63;
    int ct = (f2 >> 6) & 15;
    int q = f2 >> 10;             // 0..15 = c*2 + kt
    int kt = q & 1, c = q >> 1;
    int w = ct * 16 + (lane & 15);
    int kh = (lane >> 4) * 8;
#pragma unroll
    for (int e = 0; e < 8; ++e) {
      int kc = kt * 32 + kh + e;       // 0..63
      int seg = kc >> 5;
      int u = c * 32 + (kc & 31);
      float s  = (seg == 0) ? 0.04419417382415922f : 0.025515518153991442f;
      int off  = (seg == 0) ? 0 : 196608;
      pk.h[e] = f2bf(wgt[off + u * 256 + w] * s);
    }
    ((int4*)Bw)[fid] = pk.v;
  }
}

// Per-WAVE LDS map (int4 slots, 704/wave = 11.25 KB):
//   T1: rt*192 + kt*64 + fl   (rt 0..2, kt 0..2)
//   T0: 576 + kt*64 + fl      (kt 0..1)
#define WSLOTS 704
#define T0BASE 576

struct X1Raw { ni4 a[8]; };   // s1[8] (2 regs) + v1[8u x 3k] (6 regs), raw bits

static __device__ __forceinline__ void load_x1_asm(
    X1Raw& r, const float* __restrict__ x1, int zrow, int ub, int rr)
{
  const float* base = x1 + (size_t)zrow * 1024;
  const float* ps = base + ub + rr * 8;
  gload4(r.a[0], ps);
  gload4(r.a[1], ps + 4);
  const float* pv = base + 256 + 3 * ub + rr * 24;
#pragma unroll
  for (int i = 0; i < 6; ++i) gload4(r.a[2 + i], pv + 4 * i);
}

// thread (zl = lane>>2 0..15, rr = lane&3) owns u-run [rr*8, rr*8+8) of the
// 32-u chunk. kt = sg; fragment lane fl = ((rr<<4)|(row&15)) ^ kt ^ rr.
static __device__ __forceinline__ void build_frags(
    const X1Raw& r, int zl, int rr, float s2, const float* v2, int4* wbuf)
{
  union { float4 q[2]; float f[8]; } s1u;
  s1u.q[0] = __builtin_bit_cast(float4, r.a[0]);
  s1u.q[1] = __builtin_bit_cast(float4, r.a[1]);
  union { float4 q[6]; float f[24]; } v1u;
#pragma unroll
  for (int i = 0; i < 6; ++i) v1u.q[i] = __builtin_bit_cast(float4, r.a[2 + i]);

  // ---- T1: sg(=kt) 0..2 x comp k 0..2 ; row = 3*zl + k (0..47)
#pragma unroll
  for (int sg = 0; sg < 3; ++sg) {
#pragma unroll
    for (int k = 0; k < 3; ++k) {
      int row = 3 * zl + k;
      int fl  = (((rr << 4) | (row & 15)) ^ sg) ^ rr;
      int slot = (row >> 4) * 192 + sg * 64 + fl;
      float t[8];
      if (sg == 0) {                     // s1 * v2[k]      (-> W2)
#pragma unroll
        for (int e = 0; e < 8; ++e) t[e] = s1u.f[e] * v2[k];
      } else if (sg == 1) {              // v1[.,k] * s2    (-> W3)
#pragma unroll
        for (int e = 0; e < 8; ++e) t[e] = v1u.f[3 * e + k] * s2;
      } else {                           // (v1 x v2)[k]    (-> W5)
        int k1 = k + 1; if (k1 > 2) k1 -= 3;
        int k2 = k + 2; if (k2 > 2) k2 -= 3;
#pragma unroll
        for (int e = 0; e < 8; ++e)
          t[e] = v1u.f[3 * e + k1] * v2[k2] - v1u.f[3 * e + k2] * v2[k1];
      }
      union { unsigned short h[8]; int4 v; } pk;
#pragma unroll
      for (int e = 0; e < 8; ++e) pk.h[e] = f2bf(t[e]);
      wbuf[slot] = pk.v;
    }
  }
  // ---- T0: sg(=kt) 0..1 ; row = zl
#pragma unroll
  for (int sg = 0; sg < 2; ++sg) {
    int fl = (((rr << 4) | zl) ^ sg) ^ rr;
    int slot = T0BASE + sg * 64 + fl;
    float t[8];
    if (sg == 0) {                       // s1 * s2         (-> W1)
#pragma unroll
      for (int e = 0; e < 8; ++e) t[e] = s1u.f[e] * s2;
    } else {                             // v1 . v2         (-> W4)
#pragma unroll
      for (int e = 0; e < 8; ++e) {
        const float* p = v1u.f + 3 * e;
        t[e] = p[0] * v2[0] + p[1] * v2[1] + p[2] * v2[2];
      }
    }
    union { unsigned short h[8]; int4 v; } pk;
#pragma unroll
    for (int e = 0; e < 8; ++e) pk.h[e] = f2bf(t[e]);
    wbuf[slot] = pk.v;
  }
}

// Burst-load this wave's per-chunk B slice (asm, stays in regs): 20 int4.
// vb[kt*4+j] = out1, kt 0..2; vb[12+kt*4+j] = out0, kt 0..1; j = ct offset.
static __device__ __forceinline__ void burstB(
    ni4 (&vb)[20], const int4* __restrict__ B1v,
    const int4* __restrict__ B0v, int c, int ct0, int lane)
{
#pragma unroll
  for (int kt = 0; kt < 3; ++kt)
#pragma unroll
    for (int j = 0; j < 4; ++j)
      gload4(vb[kt * 4 + j],
             B1v + ((size_t)((c * 3 + kt) * 16 + ct0 + j)) * 64 + lane);
#pragma unroll
  for (int kt = 0; kt < 2; ++kt)
#pragma unroll
    for (int j = 0; j < 4; ++j)
      gload4(vb[12 + kt * 4 + j],
             B0v + ((size_t)((c * 2 + kt) * 16 + ct0 + j)) * 64 + lane);
}

// Pure LDS+MFMA gemm for one u-chunk: 44 MFMA. No barriers, no global loads.
static __device__ __forceinline__ void gemm_steps(
    const int4* __restrict__ wbuf, const ni4 (&vb)[20], int lane,
    f32x4 acc1[3][4], f32x4 acc0[4])
{
  __builtin_amdgcn_s_setprio(1);
#pragma unroll
  for (int kt = 0; kt < 3; ++kt) {
    int fl = (lane ^ kt) ^ (lane >> 4);
    int4 a[3];
#pragma unroll
    for (int rt = 0; rt < 3; ++rt) a[rt] = wbuf[rt * 192 + kt * 64 + fl];
#pragma unroll
    for (int rt = 0; rt < 3; ++rt) {
      bf16x8 av = asbf(a[rt]);
#pragma unroll
      for (int j = 0; j < 4; ++j)
        acc1[rt][j] = __builtin_amdgcn_mfma_f32_16x16x32_bf16(
            av, asbfn(vb[kt * 4 + j]), acc1[rt][j], 0, 0, 0);
    }
  }
#pragma unroll
  for (int kt = 0; kt < 2; ++kt) {
    int fl = (lane ^ kt) ^ (lane >> 4);
    int4 a0 = wbuf[T0BASE + kt * 64 + fl];
    bf16x8 av = asbf(a0);
#pragma unroll
    for (int j = 0; j < 4; ++j)
      acc0[j] = __builtin_amdgcn_mfma_f32_16x16x32_bf16(
          av, asbfn(vb[12 + kt * 4 + j]), acc0[j], 0, 0, 0);
  }
  __builtin_amdgcn_s_setprio(0);
}

// ---------------------------------------------------------------------------
// Main: 256 threads = 4 independent waves. Block covers one 16-z-row tile;
// wave wid covers cols [wid*64, wid*64+64). 8 u-chunks of 32. NO BARRIERS.
// ---------------------------------------------------------------------------
__global__ __launch_bounds__(256, 2) void tp_main(
    const float* __restrict__ x1, const float* __restrict__ x2,
    const int4* __restrict__ B1v, const int4* __restrict__ B0v,
    float* __restrict__ out)
{
  __shared__ int4 ldsT[4 * WSLOTS];     // 45056 bytes, wave-private quarters
  const int tid  = threadIdx.x;
  const int lane = tid & 63;
  const int wid  = tid >> 6;            // wave 0..3 = col-quarter
  const int ct0  = wid * 4;
  const int z0   = blockIdx.x * 16;
  const int zl   = lane >> 2;           // T-build row (0..15)
  const int rr   = lane & 3;            // T-build u-run (0..3)
  int4* wbuf = ldsT + wid * WSLOTS;

  f32x4 acc1[3][4];
  f32x4 acc0[4];
#pragma unroll
  for (int i = 0; i < 3; ++i)
#pragma unroll
    for (int j = 0; j < 4; ++j) acc1[i][j] = (f32x4){0.f, 0.f, 0.f, 0.f};
#pragma unroll
  for (int j = 0; j < 4; ++j) acc0[j] = (f32x4){0.f, 0.f, 0.f, 0.f};

  // x2 (16B per z-row) via asm + drain BEFORE the pipeline starts.
  ni4 x2raw;
  gload4(x2raw, x2 + (size_t)(z0 + zl) * 4);
  WAITV(0);
  float4 x2v = __builtin_bit_cast(float4, x2raw);
  const float s2 = x2v.x;
  float v2[3] = {x2v.y, x2v.z, x2v.w};

  X1Raw rX;
  ni4 vb[20];

  load_x1_asm(rX, x1, z0 + zl, 0, rr);   // x1(0): 8 outstanding

#pragma unroll 1
  for (int c = 0; c < 7; ++c) {
    burstB(vb, B1v, B0v, c, ct0, lane);  // +20 -> 28
    WAITV(20);                           // x1(c) done; B(c) in flight
    build_frags(rX, zl, rr, s2, v2, wbuf);
    load_x1_asm(rX, x1, z0 + zl, (c + 1) * 32, rr);  // +8 -> 28
    WAITV(8);                            // B(c) done; x1(c+1) in flight
    gemm_steps(wbuf, vb, lane, acc1, acc0);
  }
  // ---- tail chunk 7
  burstB(vb, B1v, B0v, 7, ct0, lane);
  WAITV(20);                             // x1(7) done
  build_frags(rX, zl, rr, s2, v2, wbuf);
  WAITV(0);                              // B(7) done
  gemm_steps(wbuf, vb, lane, acc1, acc0);

  // ---- epilogue: accumulators are the final outputs
  const int col = lane & 15;
  const int rb  = (lane >> 4) * 4;       // C/D: col=lane&15, row=(lane>>4)*4+reg
#pragma unroll
  for (int j = 0; j < 4; ++j) {
    int w = (ct0 + j) * 16 + col;
#pragma unroll
    for (int rg = 0; rg < 4; ++rg) {
      int row = rb + rg;                 // zl 0..15
      out[(size_t)(z0 + row) * 1024 + w] = acc0[j][rg];
    }
  }
#pragma unroll
  for (int rt = 0; rt < 3; ++rt) {
#pragma unroll
    for (int j = 0; j < 4; ++j) {
      int w = (ct0 + j) * 16 + col;
#pragma unroll
      for (int rg = 0; rg < 4; ++rg) {
        int row = rt * 16 + rb + rg;     // 0..47 ; row = 3*zl + k
        int zz = row / 3;
        int k  = row - zz * 3;
        out[(size_t)(z0 + zz) * 1024 + 256 + w * 3 + k] = acc1[rt][j][rg];
      }
    }
  }
}

// ---------------------------------------------------------------------------
extern "C" void kernel_launch(void* const* d_in, const int* in_sizes, int n_in,
                              void* d_out, int out_size, void* d_ws, size_t ws_size,
                              hipStream_t stream) {
  const float* x1  = (const float*)d_in[0];   // (n, 1024) f32
  const float* x2  = (const float*)d_in[1];   // (n, 4)    f32
  const float* wgt = (const float*)d_in[2];   // (327680,) f32
  float* out = (float*)d_out;                 // (n, 1024) f32

  // ws: B1 fragments [0, 393216) + B0 fragments [393216, 655360)  (bf16)
  unsigned short* Bw = (unsigned short*)d_ws;
  const int4* B1v = (const int4*)Bw;
  const int4* B0v = B1v + 24576;

  int n = in_sizes[0] / 1024;                 // 20000 (divisible by 16)

  prep_weights<<<160, 256, 0, stream>>>(wgt, Bw);
  tp_main<<<n / 16, 256, 0, stream>>>(x1, x2, B1v, B0v, out);
}